// Round 1
// baseline (210.271 us; speedup 1.0000x reference)
//
#include <hip/hip_runtime.h>
#include <hip/hip_bf16.h>

#define B_ 32
#define N_ 4096
#define C_ 256
#define W_ 64
#define OUT_ 512
#define EPS_ 1e-5f

typedef __attribute__((ext_vector_type(8))) short short8;
typedef __attribute__((ext_vector_type(4))) float floatx4;

// workspace byte offsets
#define W1F_OFF    0          // 192 f32 fused conv1 weights
#define B1F_OFF    768        // 64 f32
#define B2F_OFF    1024       // 64 f32
#define B3F_OFF    1280       // 64 f32
#define W2T_OFF    1536       // 64*72 u16 (bf16, padded rows)
#define W3T_OFF    10752      // 64*72 u16
#define WT_OFF     20480      // B*64*N u16 bf16 weights output = 16777216 B
#define AGGT_OFF   16797696   // 16384*32 f32 = 2097152 B  (aggT[c*64+w][b])
#define PREACT_OFF 18894848   // 512*32 f32 = 65536 B      (preact[o][b])
#define WS_NEEDED  (18894848 + 65536)

__device__ __forceinline__ ushort f2bf(float f) {
  unsigned u = __builtin_bit_cast(unsigned, f);
  unsigned r = (u + 0x7fffu + ((u >> 16) & 1u)) >> 16;  // RTNE
  return (ushort)r;
}

// ---------------- K0: fold BN into conv weights ----------------
__global__ void k0_fuse(const float* __restrict__ w1, const float* __restrict__ b1,
                        const float* __restrict__ g1, const float* __restrict__ be1,
                        const float* __restrict__ m1, const float* __restrict__ v1,
                        const float* __restrict__ w2, const float* __restrict__ b2,
                        const float* __restrict__ g2, const float* __restrict__ be2,
                        const float* __restrict__ m2, const float* __restrict__ v2,
                        const float* __restrict__ w3, const float* __restrict__ b3,
                        const float* __restrict__ g3, const float* __restrict__ be3,
                        const float* __restrict__ m3, const float* __restrict__ v3,
                        char* __restrict__ ws) {
  int w = threadIdx.x;
  if (w >= 64) return;
  float* w1f = (float*)(ws + W1F_OFF);
  float* b1f = (float*)(ws + B1F_OFF);
  float* b2f = (float*)(ws + B2F_OFF);
  float* b3f = (float*)(ws + B3F_OFF);
  ushort* w2t = (ushort*)(ws + W2T_OFF);
  ushort* w3t = (ushort*)(ws + W3T_OFF);

  float s1 = g1[w] * rsqrtf(v1[w] + EPS_);
  for (int j = 0; j < 3; ++j) w1f[w * 3 + j] = w1[w * 3 + j] * s1;
  b1f[w] = (b1[w] - m1[w]) * s1 + be1[w];

  float s2 = g2[w] * rsqrtf(v2[w] + EPS_);
  for (int k = 0; k < 64; ++k) w2t[w * 72 + k] = f2bf(w2[w * 64 + k] * s2);
  for (int k = 64; k < 72; ++k) w2t[w * 72 + k] = 0;
  b2f[w] = (b2[w] - m2[w]) * s2 + be2[w];

  float s3 = g3[w] * rsqrtf(v3[w] + EPS_);
  for (int k = 0; k < 64; ++k) w3t[w * 72 + k] = f2bf(w3[w * 64 + k] * s3);
  for (int k = 64; k < 72; ++k) w3t[w * 72 + k] = 0;
  b3f[w] = (b3[w] - m3[w]) * s3 + be3[w];
}

// ---------------- K1: WeightNet (layer1 scalar, layers 2/3 MFMA) ----------------
// block = 256 threads (4 waves), 256 points; each wave owns its 64 points
// (no cross-wave LDS sharing of h -> no extra syncthreads needed after phase A).
__global__ __launch_bounds__(256) void k1_weightnet(const float* __restrict__ xyz,
                                                    char* __restrict__ ws) {
  // h rows padded to 72 u16 = 144 B = 9*16 B -> b128 frag reads are 2-way max (free)
  __shared__ __align__(16) ushort h_lds[256 * 72];
  __shared__ __align__(16) ushort w2_lds[64 * 72];
  __shared__ __align__(16) ushort w3_lds[64 * 72];
  __shared__ float b2_lds[64];
  __shared__ float b3_lds[64];

  const int t = threadIdx.x;
  const int blk = blockIdx.x;
  const int b = blk >> 4;
  const int n0 = (blk & 15) << 8;

  // stage fused weights into LDS (9216 B each = 2304 words)
  const unsigned* w2src = (const unsigned*)(ws + W2T_OFF);
  const unsigned* w3src = (const unsigned*)(ws + W3T_OFF);
  unsigned* w2d = (unsigned*)w2_lds;
  unsigned* w3d = (unsigned*)w3_lds;
#pragma unroll
  for (int i = 0; i < 9; ++i) {
    w2d[t + i * 256] = w2src[t + i * 256];
    w3d[t + i * 256] = w3src[t + i * 256];
  }
  if (t < 64) {
    b2_lds[t] = ((const float*)(ws + B2F_OFF))[t];
    b3_lds[t] = ((const float*)(ws + B3F_OFF))[t];
  }

  // ---- phase A: layer 1 (K=3), one point per thread, write h1 bf16 to LDS ----
  const float* w1f = (const float*)(ws + W1F_OFF);
  const float* b1f = (const float*)(ws + B1F_OFF);
  const int n = n0 + t;
  const float* xp = xyz + ((size_t)b * N_ + n) * 3;
  float x0 = xp[0], x1 = xp[1], x2 = xp[2];
  unsigned* hrow = (unsigned*)&h_lds[t * 72];
#pragma unroll 4
  for (int cp = 0; cp < 32; ++cp) {
    int c0 = cp * 2, c1 = cp * 2 + 1;
    float a0 = fmaxf(b1f[c0] + w1f[c0 * 3] * x0 + w1f[c0 * 3 + 1] * x1 + w1f[c0 * 3 + 2] * x2, 0.f);
    float a1 = fmaxf(b1f[c1] + w1f[c1 * 3] * x0 + w1f[c1 * 3 + 1] * x1 + w1f[c1 * 3 + 2] * x2, 0.f);
    hrow[cp] = (unsigned)f2bf(a0) | ((unsigned)f2bf(a1) << 16);
  }
  __syncthreads();  // weight staging + all h1 visible

  const int wv = t >> 6, lane = t & 63;
  const int lrow = lane & 15, lk = lane >> 4;

  // ---- layer 2: per-wave GEMM 64pts x 64ch, K=64 ----
  floatx4 acc[4][4];
#pragma unroll
  for (int mt = 0; mt < 4; ++mt)
#pragma unroll
    for (int nt = 0; nt < 4; ++nt) acc[mt][nt] = (floatx4){0.f, 0.f, 0.f, 0.f};

#pragma unroll
  for (int ks = 0; ks < 2; ++ks) {
    short8 afr[4], bfr[4];
#pragma unroll
    for (int mt = 0; mt < 4; ++mt)
      afr[mt] = *(const short8*)&h_lds[(wv * 64 + mt * 16 + lrow) * 72 + ks * 32 + lk * 8];
#pragma unroll
    for (int nt = 0; nt < 4; ++nt)
      bfr[nt] = *(const short8*)&w2_lds[(nt * 16 + lrow) * 72 + ks * 32 + lk * 8];
#pragma unroll
    for (int mt = 0; mt < 4; ++mt)
#pragma unroll
      for (int nt = 0; nt < 4; ++nt)
        acc[mt][nt] = __builtin_amdgcn_mfma_f32_16x16x32_bf16(afr[mt], bfr[nt], acc[mt][nt], 0, 0, 0);
  }
  // epilogue: bias+relu -> h2 (same wave-private LDS region; reads all precede writes)
#pragma unroll
  for (int mt = 0; mt < 4; ++mt)
#pragma unroll
    for (int nt = 0; nt < 4; ++nt) {
      float bias = b2_lds[nt * 16 + lrow];
#pragma unroll
      for (int r = 0; r < 4; ++r) {
        float v = fmaxf(acc[mt][nt][r] + bias, 0.f);
        // C/D: col = lane&15 (=ch), row = (lane>>4)*4+r (=pt)
        h_lds[(wv * 64 + mt * 16 + lk * 4 + r) * 72 + nt * 16 + lrow] = f2bf(v);
      }
    }

  // ---- layer 3 ----
  floatx4 acc3[4][4];
#pragma unroll
  for (int mt = 0; mt < 4; ++mt)
#pragma unroll
    for (int nt = 0; nt < 4; ++nt) acc3[mt][nt] = (floatx4){0.f, 0.f, 0.f, 0.f};

#pragma unroll
  for (int ks = 0; ks < 2; ++ks) {
    short8 afr[4], bfr[4];
#pragma unroll
    for (int mt = 0; mt < 4; ++mt)
      afr[mt] = *(const short8*)&h_lds[(wv * 64 + mt * 16 + lrow) * 72 + ks * 32 + lk * 8];
#pragma unroll
    for (int nt = 0; nt < 4; ++nt)
      bfr[nt] = *(const short8*)&w3_lds[(nt * 16 + lrow) * 72 + ks * 32 + lk * 8];
#pragma unroll
    for (int mt = 0; mt < 4; ++mt)
#pragma unroll
      for (int nt = 0; nt < 4; ++nt)
        acc3[mt][nt] = __builtin_amdgcn_mfma_f32_16x16x32_bf16(afr[mt], bfr[nt], acc3[mt][nt], 0, 0, 0);
  }
  // epilogue: bias+relu -> global wt[b][ch][n] bf16 (B^T layout for K2)
  ushort* wt = (ushort*)(ws + WT_OFF);
#pragma unroll
  for (int mt = 0; mt < 4; ++mt)
#pragma unroll
    for (int nt = 0; nt < 4; ++nt) {
      float bias = b3_lds[nt * 16 + lrow];
#pragma unroll
      for (int r = 0; r < 4; ++r) {
        float v = fmaxf(acc3[mt][nt][r] + bias, 0.f);
        int pt = mt * 16 + lk * 4 + r;
        int ch = nt * 16 + lrow;
        wt[(size_t)(b * W_ + ch) * N_ + n0 + wv * 64 + pt] = f2bf(v);
      }
    }
}

// ---------------- K2: agg[b][c][w] = sum_n feat[b][c][n] * wt[b][w][n] ----------------
// 1 wave per block; blk -> (b, c-tile of 16, k-split of 1024); atomics into aggT[cw][b]
__global__ __launch_bounds__(64) void k2_agg(const float* __restrict__ feature,
                                             char* __restrict__ ws) {
  const int blk = blockIdx.x;
  const int b = blk >> 6;
  const int ct = (blk >> 2) & 15;
  const int kb = blk & 3;
  const int lane = threadIdx.x;
  const int lrow = lane & 15, lk = lane >> 4;
  const int c_base = ct * 16;
  const int k_base = kb * 1024;

  const ushort* wt = (const ushort*)(ws + WT_OFF);
  const float* fp = feature + (size_t)(b * C_ + c_base + lrow) * N_ + lk * 8;
  const ushort* wp[4];
#pragma unroll
  for (int nt = 0; nt < 4; ++nt)
    wp[nt] = wt + (size_t)(b * W_ + nt * 16 + lrow) * N_ + lk * 8;

  floatx4 acc[4];
#pragma unroll
  for (int nt = 0; nt < 4; ++nt) acc[nt] = (floatx4){0.f, 0.f, 0.f, 0.f};

#pragma unroll 2
  for (int k0 = k_base; k0 < k_base + 1024; k0 += 32) {
    float4 f0 = *(const float4*)(fp + k0);
    float4 f1 = *(const float4*)(fp + k0 + 4);
    union { unsigned u[4]; short8 s; } au;
    au.u[0] = (unsigned)f2bf(f0.x) | ((unsigned)f2bf(f0.y) << 16);
    au.u[1] = (unsigned)f2bf(f0.z) | ((unsigned)f2bf(f0.w) << 16);
    au.u[2] = (unsigned)f2bf(f1.x) | ((unsigned)f2bf(f1.y) << 16);
    au.u[3] = (unsigned)f2bf(f1.z) | ((unsigned)f2bf(f1.w) << 16);
#pragma unroll
    for (int nt = 0; nt < 4; ++nt) {
      short8 bfr = *(const short8*)(wp[nt] + k0);
      acc[nt] = __builtin_amdgcn_mfma_f32_16x16x32_bf16(au.s, bfr, acc[nt], 0, 0, 0);
    }
  }

  float* aggT = (float*)(ws + AGGT_OFF);
#pragma unroll
  for (int nt = 0; nt < 4; ++nt)
#pragma unroll
    for (int r = 0; r < 4; ++r) {
      int c = c_base + lk * 4 + r;       // row = (lane>>4)*4 + r
      int wcol = nt * 16 + lrow;         // col = lane&15
      atomicAdd(&aggT[(c * W_ + wcol) * B_ + b], acc[nt][r] * (1.f / 4096.f));
    }
}

// ---------------- K3: preact[o][b] = sum_cw wf[o][cw] * aggT[cw][b] ----------------
// blk -> (o-tile of 64, k-split of 512); LDS-tiled; atomics into preact
__global__ __launch_bounds__(256) void k3_final(const float* __restrict__ wf,
                                                char* __restrict__ ws) {
  __shared__ __align__(16) float wfl[64][68];  // 272 B rows: aligned + conflict-benign
  __shared__ __align__(16) float agl[64][32];
  const int t = threadIdx.x;
  const int ot = blockIdx.x >> 5;
  const int kb = blockIdx.x & 31;
  const int o_base = ot * 64;
  const int k_base = kb * 512;
  const float* aggT = (const float*)(ws + AGGT_OFF);

  const int og = t >> 3, bg = t & 7;     // og 0..31 (o-pair), bg 0..7 (4 b's)
  float a00 = 0.f, a01 = 0.f, a02 = 0.f, a03 = 0.f;
  float a10 = 0.f, a11 = 0.f, a12 = 0.f, a13 = 0.f;

  const int lr = t >> 2;                 // 0..63 load row
  const int lc = (t & 3) * 16;           // wf load col group
  const int ac = (t & 3) * 8;            // agl load col group

  for (int kc = 0; kc < 8; ++kc) {
    int k0 = k_base + kc * 64;
#pragma unroll
    for (int q = 0; q < 4; ++q)
      *(float4*)&wfl[lr][lc + q * 4] =
          *(const float4*)&wf[(size_t)(o_base + lr) * 16384 + k0 + lc + q * 4];
#pragma unroll
    for (int q = 0; q < 2; ++q)
      *(float4*)&agl[lr][ac + q * 4] =
          *(const float4*)&aggT[(size_t)(k0 + lr) * 32 + ac + q * 4];
    __syncthreads();
#pragma unroll 8
    for (int k = 0; k < 64; ++k) {
      float w0 = wfl[og * 2][k];
      float w1 = wfl[og * 2 + 1][k];
      float4 av = *(const float4*)&agl[k][bg * 4];
      a00 += w0 * av.x; a01 += w0 * av.y; a02 += w0 * av.z; a03 += w0 * av.w;
      a10 += w1 * av.x; a11 += w1 * av.y; a12 += w1 * av.z; a13 += w1 * av.w;
    }
    __syncthreads();
  }
  float* preact = (float*)(ws + PREACT_OFF);
  int o0 = o_base + og * 2;
  int bb = bg * 4;
  atomicAdd(&preact[o0 * 32 + bb + 0], a00);
  atomicAdd(&preact[o0 * 32 + bb + 1], a01);
  atomicAdd(&preact[o0 * 32 + bb + 2], a02);
  atomicAdd(&preact[o0 * 32 + bb + 3], a03);
  atomicAdd(&preact[(o0 + 1) * 32 + bb + 0], a10);
  atomicAdd(&preact[(o0 + 1) * 32 + bb + 1], a11);
  atomicAdd(&preact[(o0 + 1) * 32 + bb + 2], a12);
  atomicAdd(&preact[(o0 + 1) * 32 + bb + 3], a13);
}

// ---------------- K4: final BN + ReLU ----------------
__global__ void k4_finalize(const float* __restrict__ bf, const float* __restrict__ gf,
                            const float* __restrict__ bef, const float* __restrict__ mf,
                            const float* __restrict__ vf, const char* __restrict__ ws,
                            float* __restrict__ out) {
  int i = blockIdx.x * 256 + threadIdx.x;  // 0..16383
  int o = i >> 5, b = i & 31;
  const float* preact = (const float*)(ws + PREACT_OFF);
  float v = preact[i];
  float s = gf[o] * rsqrtf(vf[o] + EPS_);
  float r = (v + bf[o] - mf[o]) * s + bef[o];
  out[b * OUT_ + o] = fmaxf(r, 0.f);
}

extern "C" void kernel_launch(void* const* d_in, const int* in_sizes, int n_in,
                              void* d_out, int out_size, void* d_ws, size_t ws_size,
                              hipStream_t stream) {
  const float* xyz     = (const float*)d_in[0];
  const float* feature = (const float*)d_in[1];
  // d_in[2] = idx (int64) — unused by the reference
  const float* w1 = (const float*)d_in[3];
  const float* b1 = (const float*)d_in[4];
  const float* g1 = (const float*)d_in[5];
  const float* be1 = (const float*)d_in[6];
  const float* m1 = (const float*)d_in[7];
  const float* v1 = (const float*)d_in[8];
  const float* w2 = (const float*)d_in[9];
  const float* b2 = (const float*)d_in[10];
  const float* g2 = (const float*)d_in[11];
  const float* be2 = (const float*)d_in[12];
  const float* m2 = (const float*)d_in[13];
  const float* v2 = (const float*)d_in[14];
  const float* w3 = (const float*)d_in[15];
  const float* b3 = (const float*)d_in[16];
  const float* g3 = (const float*)d_in[17];
  const float* be3 = (const float*)d_in[18];
  const float* m3 = (const float*)d_in[19];
  const float* v3 = (const float*)d_in[20];
  const float* wf = (const float*)d_in[21];
  const float* bf = (const float*)d_in[22];
  const float* gf = (const float*)d_in[23];
  const float* bef = (const float*)d_in[24];
  const float* mf = (const float*)d_in[25];
  const float* vf = (const float*)d_in[26];

  char* ws = (char*)d_ws;
  if (ws_size < (size_t)WS_NEEDED) return;

  // zero accumulation buffers (aggT + preact are contiguous)
  hipMemsetAsync(ws + AGGT_OFF, 0, 2097152 + 65536, stream);

  k0_fuse<<<1, 64, 0, stream>>>(w1, b1, g1, be1, m1, v1,
                                w2, b2, g2, be2, m2, v2,
                                w3, b3, g3, be3, m3, v3, ws);
  k1_weightnet<<<512, 256, 0, stream>>>(xyz, ws);
  k2_agg<<<2048, 64, 0, stream>>>(feature, ws);
  k3_final<<<256, 256, 0, stream>>>(wf, ws);
  k4_finalize<<<64, 256, 0, stream>>>(bf, gf, bef, mf, vf, ws, (float*)d_out);
}

// Round 2
// 120.240 us; speedup vs baseline: 1.7488x; 1.7488x over previous
//
#include <hip/hip_runtime.h>
#include <hip/hip_bf16.h>

#define B_ 32
#define N_ 4096
#define C_ 256
#define W_ 64
#define OUT_ 512
#define EPS_ 1e-5f

typedef __attribute__((ext_vector_type(8))) short short8;
typedef __attribute__((ext_vector_type(4))) float floatx4;

// workspace byte offsets
#define W1F_OFF    0          // 192 f32 fused conv1 weights
#define B1F_OFF    768        // 64 f32
#define B2F_OFF    1024       // 64 f32
#define B3F_OFF    1280       // 64 f32
#define W2T_OFF    1536       // 64*72 u16 (bf16, padded rows)
#define W3T_OFF    10752      // 64*72 u16
#define WT_OFF     20480      // B*64*N u16 bf16 weights output = 16777216 B
#define AGGT_OFF   16797696   // up to 4 slabs of 16384*32 f32 (2 MB each)
#define SLAB_FLTS  524288     // 16384*32
#define PRE4_OFF   (16797696 + 4*2097152)   // preact when 4 slabs fit
#define PRE1_OFF   (16797696 + 1*2097152)   // preact in atomic fallback
#define WS_NEED4   (PRE4_OFF + 65536)
#define WS_NEED1   (PRE1_OFF + 65536)

__device__ __forceinline__ ushort f2bf(float f) {
  unsigned u = __builtin_bit_cast(unsigned, f);
  unsigned r = (u + 0x7fffu + ((u >> 16) & 1u)) >> 16;  // RTNE
  return (ushort)r;
}

// ---------------- K0: fold BN into conv weights ----------------
__global__ void k0_fuse(const float* __restrict__ w1, const float* __restrict__ b1,
                        const float* __restrict__ g1, const float* __restrict__ be1,
                        const float* __restrict__ m1, const float* __restrict__ v1,
                        const float* __restrict__ w2, const float* __restrict__ b2,
                        const float* __restrict__ g2, const float* __restrict__ be2,
                        const float* __restrict__ m2, const float* __restrict__ v2,
                        const float* __restrict__ w3, const float* __restrict__ b3,
                        const float* __restrict__ g3, const float* __restrict__ be3,
                        const float* __restrict__ m3, const float* __restrict__ v3,
                        char* __restrict__ ws) {
  int w = threadIdx.x;
  if (w >= 64) return;
  float* w1f = (float*)(ws + W1F_OFF);
  float* b1f = (float*)(ws + B1F_OFF);
  float* b2f = (float*)(ws + B2F_OFF);
  float* b3f = (float*)(ws + B3F_OFF);
  ushort* w2t = (ushort*)(ws + W2T_OFF);
  ushort* w3t = (ushort*)(ws + W3T_OFF);

  float s1 = g1[w] * rsqrtf(v1[w] + EPS_);
  for (int j = 0; j < 3; ++j) w1f[w * 3 + j] = w1[w * 3 + j] * s1;
  b1f[w] = (b1[w] - m1[w]) * s1 + be1[w];

  float s2 = g2[w] * rsqrtf(v2[w] + EPS_);
  for (int k = 0; k < 64; ++k) w2t[w * 72 + k] = f2bf(w2[w * 64 + k] * s2);
  for (int k = 64; k < 72; ++k) w2t[w * 72 + k] = 0;
  b2f[w] = (b2[w] - m2[w]) * s2 + be2[w];

  float s3 = g3[w] * rsqrtf(v3[w] + EPS_);
  for (int k = 0; k < 64; ++k) w3t[w * 72 + k] = f2bf(w3[w * 64 + k] * s3);
  for (int k = 64; k < 72; ++k) w3t[w * 72 + k] = 0;
  b3f[w] = (b3[w] - m3[w]) * s3 + be3[w];
}

// ---------------- K1: WeightNet (layer1 scalar, layers 2/3 MFMA) ----------------
__global__ __launch_bounds__(256) void k1_weightnet(const float* __restrict__ xyz,
                                                    char* __restrict__ ws) {
  __shared__ __align__(16) ushort h_lds[256 * 72];
  __shared__ __align__(16) ushort w2_lds[64 * 72];
  __shared__ __align__(16) ushort w3_lds[64 * 72];
  __shared__ float b2_lds[64];
  __shared__ float b3_lds[64];

  const int t = threadIdx.x;
  const int blk = blockIdx.x;
  const int b = blk >> 4;
  const int n0 = (blk & 15) << 8;

  const unsigned* w2src = (const unsigned*)(ws + W2T_OFF);
  const unsigned* w3src = (const unsigned*)(ws + W3T_OFF);
  unsigned* w2d = (unsigned*)w2_lds;
  unsigned* w3d = (unsigned*)w3_lds;
#pragma unroll
  for (int i = 0; i < 9; ++i) {
    w2d[t + i * 256] = w2src[t + i * 256];
    w3d[t + i * 256] = w3src[t + i * 256];
  }
  if (t < 64) {
    b2_lds[t] = ((const float*)(ws + B2F_OFF))[t];
    b3_lds[t] = ((const float*)(ws + B3F_OFF))[t];
  }

  const float* w1f = (const float*)(ws + W1F_OFF);
  const float* b1f = (const float*)(ws + B1F_OFF);
  const int n = n0 + t;
  const float* xp = xyz + ((size_t)b * N_ + n) * 3;
  float x0 = xp[0], x1 = xp[1], x2 = xp[2];
  unsigned* hrow = (unsigned*)&h_lds[t * 72];
#pragma unroll 4
  for (int cp = 0; cp < 32; ++cp) {
    int c0 = cp * 2, c1 = cp * 2 + 1;
    float a0 = fmaxf(b1f[c0] + w1f[c0 * 3] * x0 + w1f[c0 * 3 + 1] * x1 + w1f[c0 * 3 + 2] * x2, 0.f);
    float a1 = fmaxf(b1f[c1] + w1f[c1 * 3] * x0 + w1f[c1 * 3 + 1] * x1 + w1f[c1 * 3 + 2] * x2, 0.f);
    hrow[cp] = (unsigned)f2bf(a0) | ((unsigned)f2bf(a1) << 16);
  }
  __syncthreads();

  const int wv = t >> 6, lane = t & 63;
  const int lrow = lane & 15, lk = lane >> 4;

  floatx4 acc[4][4];
#pragma unroll
  for (int mt = 0; mt < 4; ++mt)
#pragma unroll
    for (int nt = 0; nt < 4; ++nt) acc[mt][nt] = (floatx4){0.f, 0.f, 0.f, 0.f};

#pragma unroll
  for (int ks = 0; ks < 2; ++ks) {
    short8 afr[4], bfr[4];
#pragma unroll
    for (int mt = 0; mt < 4; ++mt)
      afr[mt] = *(const short8*)&h_lds[(wv * 64 + mt * 16 + lrow) * 72 + ks * 32 + lk * 8];
#pragma unroll
    for (int nt = 0; nt < 4; ++nt)
      bfr[nt] = *(const short8*)&w2_lds[(nt * 16 + lrow) * 72 + ks * 32 + lk * 8];
#pragma unroll
    for (int mt = 0; mt < 4; ++mt)
#pragma unroll
      for (int nt = 0; nt < 4; ++nt)
        acc[mt][nt] = __builtin_amdgcn_mfma_f32_16x16x32_bf16(afr[mt], bfr[nt], acc[mt][nt], 0, 0, 0);
  }
#pragma unroll
  for (int mt = 0; mt < 4; ++mt)
#pragma unroll
    for (int nt = 0; nt < 4; ++nt) {
      float bias = b2_lds[nt * 16 + lrow];
#pragma unroll
      for (int r = 0; r < 4; ++r) {
        float v = fmaxf(acc[mt][nt][r] + bias, 0.f);
        h_lds[(wv * 64 + mt * 16 + lk * 4 + r) * 72 + nt * 16 + lrow] = f2bf(v);
      }
    }

  floatx4 acc3[4][4];
#pragma unroll
  for (int mt = 0; mt < 4; ++mt)
#pragma unroll
    for (int nt = 0; nt < 4; ++nt) acc3[mt][nt] = (floatx4){0.f, 0.f, 0.f, 0.f};

#pragma unroll
  for (int ks = 0; ks < 2; ++ks) {
    short8 afr[4], bfr[4];
#pragma unroll
    for (int mt = 0; mt < 4; ++mt)
      afr[mt] = *(const short8*)&h_lds[(wv * 64 + mt * 16 + lrow) * 72 + ks * 32 + lk * 8];
#pragma unroll
    for (int nt = 0; nt < 4; ++nt)
      bfr[nt] = *(const short8*)&w3_lds[(nt * 16 + lrow) * 72 + ks * 32 + lk * 8];
#pragma unroll
    for (int mt = 0; mt < 4; ++mt)
#pragma unroll
      for (int nt = 0; nt < 4; ++nt)
        acc3[mt][nt] = __builtin_amdgcn_mfma_f32_16x16x32_bf16(afr[mt], bfr[nt], acc3[mt][nt], 0, 0, 0);
  }
  ushort* wt = (ushort*)(ws + WT_OFF);
#pragma unroll
  for (int mt = 0; mt < 4; ++mt)
#pragma unroll
    for (int nt = 0; nt < 4; ++nt) {
      float bias = b3_lds[nt * 16 + lrow];
#pragma unroll
      for (int r = 0; r < 4; ++r) {
        float v = fmaxf(acc3[mt][nt][r] + bias, 0.f);
        int pt = mt * 16 + lk * 4 + r;
        int ch = nt * 16 + lrow;
        wt[(size_t)(b * W_ + ch) * N_ + n0 + wv * 64 + pt] = f2bf(v);
      }
    }
}

// ---------------- K2: agg[b][c][w] = sum_n feat[b][c][n]/N * wt[b][w][n] ----------------
// 512 blocks (b x 4 ct x 4 ks), 4 waves. Wave wv owns w-rows [wv*16,+16), 64 c rows.
// Feature staged to LDS bf16 double-buffer; T14 issue-early/write-late pipeline.
template <bool ATOMIC>
__global__ __launch_bounds__(256) void k2_agg(const float* __restrict__ feature,
                                              char* __restrict__ ws) {
  __shared__ __align__(16) ushort fbuf[2][64][136];  // 128 + 8 pad (16B) per row
  const int t = threadIdx.x;
  const int wv = t >> 6, lane = t & 63;
  const int lrow = lane & 15, lk = lane >> 4;
  const int blk = blockIdx.x;
  const int b = blk >> 4;
  const int ct = (blk >> 2) & 3;
  const int ks = blk & 3;

  const ushort* wt = (const ushort*)(ws + WT_OFF);
  const int srow = wv * 16 + (lane >> 2);      // staging row within 64-row tile
  const int scol = (lane & 3) * 32;            // staging col base (32 floats/lane)
  const float* fp = feature + ((size_t)(b * C_ + ct * 64 + srow)) * N_ + ks * 1024 + scol;
  const ushort* wtp = wt + ((size_t)(b * W_ + wv * 16 + lrow)) * N_ + ks * 1024 + lk * 8;

  float fr[32];

  floatx4 acc[4];
#pragma unroll
  for (int m = 0; m < 4; ++m) acc[m] = (floatx4){0.f, 0.f, 0.f, 0.f};

  // prologue: stage phase 0
#pragma unroll
  for (int q = 0; q < 8; ++q) *(float4*)&fr[q * 4] = *(const float4*)(fp + q * 4);
#pragma unroll
  for (int wq = 0; wq < 4; ++wq) {
    union { unsigned u[4]; short8 s8; } pk;
#pragma unroll
    for (int i = 0; i < 4; ++i) {
      int e = wq * 8 + i * 2;
      pk.u[i] = (unsigned)f2bf(fr[e]) | ((unsigned)f2bf(fr[e + 1]) << 16);
    }
    *(short8*)&fbuf[0][srow][scol + wq * 8] = pk.s8;
  }
  __syncthreads();

  for (int p = 0; p < 8; ++p) {
    // wt fragments for this phase (oldest in vmem queue)
    short8 wreg[4];
#pragma unroll
    for (int s = 0; s < 4; ++s)
      wreg[s] = *(const short8*)(wtp + p * 128 + s * 32);
    // issue next phase's feature loads early (stay in flight through compute)
    if (p < 7) {
#pragma unroll
      for (int q = 0; q < 8; ++q)
        *(float4*)&fr[q * 4] = *(const float4*)(fp + (p + 1) * 128 + q * 4);
    }
    // compute on current buffer
    const ushort* base = &fbuf[p & 1][0][0];
#pragma unroll
    for (int s = 0; s < 4; ++s) {
#pragma unroll
      for (int m = 0; m < 4; ++m) {
        short8 a = *(const short8*)(base + (m * 16 + lrow) * 136 + s * 32 + lk * 8);
        acc[m] = __builtin_amdgcn_mfma_f32_16x16x32_bf16(a, wreg[s], acc[m], 0, 0, 0);
      }
    }
    // pack + write next buffer (vmcnt(0) here, after latency was hidden)
    if (p < 7) {
#pragma unroll
      for (int wq = 0; wq < 4; ++wq) {
        union { unsigned u[4]; short8 s8; } pk;
#pragma unroll
        for (int i = 0; i < 4; ++i) {
          int e = wq * 8 + i * 2;
          pk.u[i] = (unsigned)f2bf(fr[e]) | ((unsigned)f2bf(fr[e + 1]) << 16);
        }
        *(short8*)&fbuf[(p + 1) & 1][srow][scol + wq * 8] = pk.s8;
      }
    }
    __syncthreads();
  }

  const float sc = 1.f / 4096.f;
  if (!ATOMIC) {
    float* slab = (float*)(ws + AGGT_OFF) + (size_t)ks * SLAB_FLTS;
#pragma unroll
    for (int m = 0; m < 4; ++m)
#pragma unroll
      for (int r = 0; r < 4; ++r) {
        int c = ct * 64 + m * 16 + lk * 4 + r;
        int w = wv * 16 + lrow;
        slab[(size_t)(c * W_ + w) * B_ + b] = acc[m][r] * sc;
      }
  } else {
    float* slab = (float*)(ws + AGGT_OFF);
#pragma unroll
    for (int m = 0; m < 4; ++m)
#pragma unroll
      for (int r = 0; r < 4; ++r) {
        int c = ct * 64 + m * 16 + lk * 4 + r;
        int w = wv * 16 + lrow;
        atomicAdd(&slab[(size_t)(c * W_ + w) * B_ + b], acc[m][r] * sc);
      }
  }
}

// ---------------- K3: preact[o][b] = sum_cw wf[o][cw] * (sum_slabs aggT) ----------------
__global__ __launch_bounds__(256) void k3_final(const float* __restrict__ wf,
                                                const char* __restrict__ ws,
                                                float* __restrict__ preact, int nslab) {
  __shared__ __align__(16) float wfl[64][68];
  __shared__ __align__(16) float agl[64][32];
  const int t = threadIdx.x;
  const int ot = blockIdx.x >> 5;
  const int kb = blockIdx.x & 31;
  const int o_base = ot * 64;
  const int k_base = kb * 512;
  const float* aggT = (const float*)(ws + AGGT_OFF);

  const int og = t >> 3, bg = t & 7;
  float a00 = 0.f, a01 = 0.f, a02 = 0.f, a03 = 0.f;
  float a10 = 0.f, a11 = 0.f, a12 = 0.f, a13 = 0.f;

  const int lr = t >> 2;
  const int lc = (t & 3) * 16;
  const int ac = (t & 3) * 8;

  for (int kc = 0; kc < 8; ++kc) {
    int k0 = k_base + kc * 64;
#pragma unroll
    for (int q = 0; q < 4; ++q)
      *(float4*)&wfl[lr][lc + q * 4] =
          *(const float4*)&wf[(size_t)(o_base + lr) * 16384 + k0 + lc + q * 4];
#pragma unroll
    for (int q = 0; q < 2; ++q) {
      size_t idx = (size_t)(k0 + lr) * 32 + ac + q * 4;
      float4 v = *(const float4*)&aggT[idx];
      for (int s = 1; s < nslab; ++s) {
        float4 u = *(const float4*)&aggT[(size_t)s * SLAB_FLTS + idx];
        v.x += u.x; v.y += u.y; v.z += u.z; v.w += u.w;
      }
      *(float4*)&agl[lr][ac + q * 4] = v;
    }
    __syncthreads();
#pragma unroll 8
    for (int k = 0; k < 64; ++k) {
      float w0 = wfl[og * 2][k];
      float w1 = wfl[og * 2 + 1][k];
      float4 av = *(const float4*)&agl[k][bg * 4];
      a00 += w0 * av.x; a01 += w0 * av.y; a02 += w0 * av.z; a03 += w0 * av.w;
      a10 += w1 * av.x; a11 += w1 * av.y; a12 += w1 * av.z; a13 += w1 * av.w;
    }
    __syncthreads();
  }
  int o0 = o_base + og * 2;
  int bb = bg * 4;
  atomicAdd(&preact[o0 * 32 + bb + 0], a00);
  atomicAdd(&preact[o0 * 32 + bb + 1], a01);
  atomicAdd(&preact[o0 * 32 + bb + 2], a02);
  atomicAdd(&preact[o0 * 32 + bb + 3], a03);
  atomicAdd(&preact[(o0 + 1) * 32 + bb + 0], a10);
  atomicAdd(&preact[(o0 + 1) * 32 + bb + 1], a11);
  atomicAdd(&preact[(o0 + 1) * 32 + bb + 2], a12);
  atomicAdd(&preact[(o0 + 1) * 32 + bb + 3], a13);
}

// ---------------- K4: final BN + ReLU ----------------
__global__ void k4_finalize(const float* __restrict__ bf, const float* __restrict__ gf,
                            const float* __restrict__ bef, const float* __restrict__ mf,
                            const float* __restrict__ vf, const float* __restrict__ preact,
                            float* __restrict__ out) {
  int i = blockIdx.x * 256 + threadIdx.x;  // 0..16383
  int o = i >> 5, b = i & 31;
  float v = preact[i];
  float s = gf[o] * rsqrtf(vf[o] + EPS_);
  float r = (v + bf[o] - mf[o]) * s + bef[o];
  out[b * OUT_ + o] = fmaxf(r, 0.f);
}

extern "C" void kernel_launch(void* const* d_in, const int* in_sizes, int n_in,
                              void* d_out, int out_size, void* d_ws, size_t ws_size,
                              hipStream_t stream) {
  const float* xyz     = (const float*)d_in[0];
  const float* feature = (const float*)d_in[1];
  const float* w1 = (const float*)d_in[3];
  const float* b1 = (const float*)d_in[4];
  const float* g1 = (const float*)d_in[5];
  const float* be1 = (const float*)d_in[6];
  const float* m1 = (const float*)d_in[7];
  const float* v1 = (const float*)d_in[8];
  const float* w2 = (const float*)d_in[9];
  const float* b2 = (const float*)d_in[10];
  const float* g2 = (const float*)d_in[11];
  const float* be2 = (const float*)d_in[12];
  const float* m2 = (const float*)d_in[13];
  const float* v2 = (const float*)d_in[14];
  const float* w3 = (const float*)d_in[15];
  const float* b3 = (const float*)d_in[16];
  const float* g3 = (const float*)d_in[17];
  const float* be3 = (const float*)d_in[18];
  const float* m3 = (const float*)d_in[19];
  const float* v3 = (const float*)d_in[20];
  const float* wf = (const float*)d_in[21];
  const float* bf = (const float*)d_in[22];
  const float* gf = (const float*)d_in[23];
  const float* bef = (const float*)d_in[24];
  const float* mf = (const float*)d_in[25];
  const float* vf = (const float*)d_in[26];

  char* ws = (char*)d_ws;
  const bool four = ws_size >= (size_t)WS_NEED4;
  if (!four && ws_size < (size_t)WS_NEED1) return;
  float* preact = (float*)(ws + (four ? PRE4_OFF : PRE1_OFF));

  // zero only what gets accumulated into
  if (four) {
    hipMemsetAsync(preact, 0, 65536, stream);
  } else {
    hipMemsetAsync(ws + AGGT_OFF, 0, 2097152 + 65536, stream);  // slab0 + preact
  }

  k0_fuse<<<1, 64, 0, stream>>>(w1, b1, g1, be1, m1, v1,
                                w2, b2, g2, be2, m2, v2,
                                w3, b3, g3, be3, m3, v3, ws);
  k1_weightnet<<<512, 256, 0, stream>>>(xyz, ws);
  if (four) {
    k2_agg<false><<<512, 256, 0, stream>>>(feature, ws);
    k3_final<<<256, 256, 0, stream>>>(wf, ws, preact, 4);
  } else {
    k2_agg<true><<<512, 256, 0, stream>>>(feature, ws);
    k3_final<<<256, 256, 0, stream>>>(wf, ws, preact, 1);
  }
  k4_finalize<<<64, 256, 0, stream>>>(bf, gf, bef, mf, vf, preact, (float*)d_out);
}

// Round 3
// 113.956 us; speedup vs baseline: 1.8452x; 1.0551x over previous
//
#include <hip/hip_runtime.h>
#include <hip/hip_bf16.h>

#define B_ 32
#define N_ 4096
#define C_ 256
#define W_ 64
#define OUT_ 512
#define EPS_ 1e-5f

typedef __attribute__((ext_vector_type(8))) short short8;
typedef __attribute__((ext_vector_type(4))) float floatx4;

// workspace byte offsets
#define W1F_OFF    0          // 192 f32 fused conv1 weights
#define B1F_OFF    768        // 64 f32
#define B2F_OFF    1024       // 64 f32
#define B3F_OFF    1280       // 64 f32
#define W2T_OFF    1536       // 64*72 u16 (bf16, padded rows)
#define W3T_OFF    10752      // 64*72 u16
#define WT_OFF     20480      // B*64*N u16 bf16 weights output = 16777216 B
#define AGGT_OFF   16797696   // up to 4 slabs of 16384*32 f32 (2 MB each)
#define SLAB_FLTS  524288     // 16384*32
#define PART_FLTS  (32*16384) // k3 partials: 32 k-splits x (o,b)
#define PART4_OFF  (16797696 + 4*2097152)
#define PART1_OFF  (16797696 + 1*2097152)
#define WS_NEED4   (PART4_OFF + PART_FLTS*4)
#define WS_NEED1   (PART1_OFF + PART_FLTS*4)

__device__ __forceinline__ ushort f2bf(float f) {
  unsigned u = __builtin_bit_cast(unsigned, f);
  unsigned r = (u + 0x7fffu + ((u >> 16) & 1u)) >> 16;  // RTNE
  return (ushort)r;
}

// ---------------- K0: fold BN into conv weights ----------------
__global__ void k0_fuse(const float* __restrict__ w1, const float* __restrict__ b1,
                        const float* __restrict__ g1, const float* __restrict__ be1,
                        const float* __restrict__ m1, const float* __restrict__ v1,
                        const float* __restrict__ w2, const float* __restrict__ b2,
                        const float* __restrict__ g2, const float* __restrict__ be2,
                        const float* __restrict__ m2, const float* __restrict__ v2,
                        const float* __restrict__ w3, const float* __restrict__ b3,
                        const float* __restrict__ g3, const float* __restrict__ be3,
                        const float* __restrict__ m3, const float* __restrict__ v3,
                        char* __restrict__ ws) {
  int w = threadIdx.x;
  if (w >= 64) return;
  float* w1f = (float*)(ws + W1F_OFF);
  float* b1f = (float*)(ws + B1F_OFF);
  float* b2f = (float*)(ws + B2F_OFF);
  float* b3f = (float*)(ws + B3F_OFF);
  ushort* w2t = (ushort*)(ws + W2T_OFF);
  ushort* w3t = (ushort*)(ws + W3T_OFF);

  float s1 = g1[w] * rsqrtf(v1[w] + EPS_);
  for (int j = 0; j < 3; ++j) w1f[w * 3 + j] = w1[w * 3 + j] * s1;
  b1f[w] = (b1[w] - m1[w]) * s1 + be1[w];

  float s2 = g2[w] * rsqrtf(v2[w] + EPS_);
  for (int k = 0; k < 64; ++k) w2t[w * 72 + k] = f2bf(w2[w * 64 + k] * s2);
  for (int k = 64; k < 72; ++k) w2t[w * 72 + k] = 0;
  b2f[w] = (b2[w] - m2[w]) * s2 + be2[w];

  float s3 = g3[w] * rsqrtf(v3[w] + EPS_);
  for (int k = 0; k < 64; ++k) w3t[w * 72 + k] = f2bf(w3[w * 64 + k] * s3);
  for (int k = 64; k < 72; ++k) w3t[w * 72 + k] = 0;
  b3f[w] = (b3[w] - m3[w]) * s3 + be3[w];
}

// ---------------- K1: WeightNet (layer1 scalar, layers 2/3 MFMA) ----------------
__global__ __launch_bounds__(256) void k1_weightnet(const float* __restrict__ xyz,
                                                    char* __restrict__ ws) {
  __shared__ __align__(16) ushort h_lds[256 * 72];
  __shared__ __align__(16) ushort w2_lds[64 * 72];
  __shared__ __align__(16) ushort w3_lds[64 * 72];
  __shared__ float b2_lds[64];
  __shared__ float b3_lds[64];

  const int t = threadIdx.x;
  const int blk = blockIdx.x;
  const int b = blk >> 4;
  const int n0 = (blk & 15) << 8;

  const unsigned* w2src = (const unsigned*)(ws + W2T_OFF);
  const unsigned* w3src = (const unsigned*)(ws + W3T_OFF);
  unsigned* w2d = (unsigned*)w2_lds;
  unsigned* w3d = (unsigned*)w3_lds;
#pragma unroll
  for (int i = 0; i < 9; ++i) {
    w2d[t + i * 256] = w2src[t + i * 256];
    w3d[t + i * 256] = w3src[t + i * 256];
  }
  if (t < 64) {
    b2_lds[t] = ((const float*)(ws + B2F_OFF))[t];
    b3_lds[t] = ((const float*)(ws + B3F_OFF))[t];
  }

  const float* w1f = (const float*)(ws + W1F_OFF);
  const float* b1f = (const float*)(ws + B1F_OFF);
  const int n = n0 + t;
  const float* xp = xyz + ((size_t)b * N_ + n) * 3;
  float x0 = xp[0], x1 = xp[1], x2 = xp[2];
  unsigned* hrow = (unsigned*)&h_lds[t * 72];
#pragma unroll 4
  for (int cp = 0; cp < 32; ++cp) {
    int c0 = cp * 2, c1 = cp * 2 + 1;
    float a0 = fmaxf(b1f[c0] + w1f[c0 * 3] * x0 + w1f[c0 * 3 + 1] * x1 + w1f[c0 * 3 + 2] * x2, 0.f);
    float a1 = fmaxf(b1f[c1] + w1f[c1 * 3] * x0 + w1f[c1 * 3 + 1] * x1 + w1f[c1 * 3 + 2] * x2, 0.f);
    hrow[cp] = (unsigned)f2bf(a0) | ((unsigned)f2bf(a1) << 16);
  }
  __syncthreads();

  const int wv = t >> 6, lane = t & 63;
  const int lrow = lane & 15, lk = lane >> 4;

  floatx4 acc[4][4];
#pragma unroll
  for (int mt = 0; mt < 4; ++mt)
#pragma unroll
    for (int nt = 0; nt < 4; ++nt) acc[mt][nt] = (floatx4){0.f, 0.f, 0.f, 0.f};

#pragma unroll
  for (int ks = 0; ks < 2; ++ks) {
    short8 afr[4], bfr[4];
#pragma unroll
    for (int mt = 0; mt < 4; ++mt)
      afr[mt] = *(const short8*)&h_lds[(wv * 64 + mt * 16 + lrow) * 72 + ks * 32 + lk * 8];
#pragma unroll
    for (int nt = 0; nt < 4; ++nt)
      bfr[nt] = *(const short8*)&w2_lds[(nt * 16 + lrow) * 72 + ks * 32 + lk * 8];
#pragma unroll
    for (int mt = 0; mt < 4; ++mt)
#pragma unroll
      for (int nt = 0; nt < 4; ++nt)
        acc[mt][nt] = __builtin_amdgcn_mfma_f32_16x16x32_bf16(afr[mt], bfr[nt], acc[mt][nt], 0, 0, 0);
  }
#pragma unroll
  for (int mt = 0; mt < 4; ++mt)
#pragma unroll
    for (int nt = 0; nt < 4; ++nt) {
      float bias = b2_lds[nt * 16 + lrow];
#pragma unroll
      for (int r = 0; r < 4; ++r) {
        float v = fmaxf(acc[mt][nt][r] + bias, 0.f);
        h_lds[(wv * 64 + mt * 16 + lk * 4 + r) * 72 + nt * 16 + lrow] = f2bf(v);
      }
    }

  floatx4 acc3[4][4];
#pragma unroll
  for (int mt = 0; mt < 4; ++mt)
#pragma unroll
    for (int nt = 0; nt < 4; ++nt) acc3[mt][nt] = (floatx4){0.f, 0.f, 0.f, 0.f};

#pragma unroll
  for (int ks = 0; ks < 2; ++ks) {
    short8 afr[4], bfr[4];
#pragma unroll
    for (int mt = 0; mt < 4; ++mt)
      afr[mt] = *(const short8*)&h_lds[(wv * 64 + mt * 16 + lrow) * 72 + ks * 32 + lk * 8];
#pragma unroll
    for (int nt = 0; nt < 4; ++nt)
      bfr[nt] = *(const short8*)&w3_lds[(nt * 16 + lrow) * 72 + ks * 32 + lk * 8];
#pragma unroll
    for (int mt = 0; mt < 4; ++mt)
#pragma unroll
      for (int nt = 0; nt < 4; ++nt)
        acc3[mt][nt] = __builtin_amdgcn_mfma_f32_16x16x32_bf16(afr[mt], bfr[nt], acc3[mt][nt], 0, 0, 0);
  }
  ushort* wt = (ushort*)(ws + WT_OFF);
#pragma unroll
  for (int mt = 0; mt < 4; ++mt)
#pragma unroll
    for (int nt = 0; nt < 4; ++nt) {
      float bias = b3_lds[nt * 16 + lrow];
#pragma unroll
      for (int r = 0; r < 4; ++r) {
        float v = fmaxf(acc3[mt][nt][r] + bias, 0.f);
        int pt = mt * 16 + lk * 4 + r;
        int ch = nt * 16 + lrow;
        wt[(size_t)(b * W_ + ch) * N_ + n0 + wv * 64 + pt] = f2bf(v);
      }
    }
}

// ---------------- K2: agg[b][c][w] = sum_n feat[b][c][n]/N * wt[b][w][n] ----------------
// 512 blocks (b x 4 ct x 4 ks), 4 waves. Wave wv owns w-rows [wv*16,+16), 64 c rows.
// Feature staged to LDS bf16 double-buffer; T14 issue-early/write-late pipeline.
template <bool ATOMIC>
__global__ __launch_bounds__(256) void k2_agg(const float* __restrict__ feature,
                                              char* __restrict__ ws) {
  __shared__ __align__(16) ushort fbuf[2][64][136];  // 128 + 8 pad (16B) per row
  const int t = threadIdx.x;
  const int wv = t >> 6, lane = t & 63;
  const int lrow = lane & 15, lk = lane >> 4;
  const int blk = blockIdx.x;
  const int b = blk >> 4;
  const int ct = (blk >> 2) & 3;
  const int ks = blk & 3;

  const ushort* wt = (const ushort*)(ws + WT_OFF);
  const int srow = wv * 16 + (lane >> 2);      // staging row within 64-row tile
  const int scol = (lane & 3) * 32;            // staging col base (32 floats/lane)
  const float* fp = feature + ((size_t)(b * C_ + ct * 64 + srow)) * N_ + ks * 1024 + scol;
  const ushort* wtp = wt + ((size_t)(b * W_ + wv * 16 + lrow)) * N_ + ks * 1024 + lk * 8;

  float fr[32];

  floatx4 acc[4];
#pragma unroll
  for (int m = 0; m < 4; ++m) acc[m] = (floatx4){0.f, 0.f, 0.f, 0.f};

  // prologue: stage phase 0
#pragma unroll
  for (int q = 0; q < 8; ++q) *(float4*)&fr[q * 4] = *(const float4*)(fp + q * 4);
#pragma unroll
  for (int wq = 0; wq < 4; ++wq) {
    union { unsigned u[4]; short8 s8; } pk;
#pragma unroll
    for (int i = 0; i < 4; ++i) {
      int e = wq * 8 + i * 2;
      pk.u[i] = (unsigned)f2bf(fr[e]) | ((unsigned)f2bf(fr[e + 1]) << 16);
    }
    *(short8*)&fbuf[0][srow][scol + wq * 8] = pk.s8;
  }
  __syncthreads();

  for (int p = 0; p < 8; ++p) {
    short8 wreg[4];
#pragma unroll
    for (int s = 0; s < 4; ++s)
      wreg[s] = *(const short8*)(wtp + p * 128 + s * 32);
    if (p < 7) {
#pragma unroll
      for (int q = 0; q < 8; ++q)
        *(float4*)&fr[q * 4] = *(const float4*)(fp + (p + 1) * 128 + q * 4);
    }
    const ushort* base = &fbuf[p & 1][0][0];
#pragma unroll
    for (int s = 0; s < 4; ++s) {
#pragma unroll
      for (int m = 0; m < 4; ++m) {
        short8 a = *(const short8*)(base + (m * 16 + lrow) * 136 + s * 32 + lk * 8);
        acc[m] = __builtin_amdgcn_mfma_f32_16x16x32_bf16(a, wreg[s], acc[m], 0, 0, 0);
      }
    }
    if (p < 7) {
#pragma unroll
      for (int wq = 0; wq < 4; ++wq) {
        union { unsigned u[4]; short8 s8; } pk;
#pragma unroll
        for (int i = 0; i < 4; ++i) {
          int e = wq * 8 + i * 2;
          pk.u[i] = (unsigned)f2bf(fr[e]) | ((unsigned)f2bf(fr[e + 1]) << 16);
        }
        *(short8*)&fbuf[(p + 1) & 1][srow][scol + wq * 8] = pk.s8;
      }
    }
    __syncthreads();
  }

  const float sc = 1.f / 4096.f;
  if (!ATOMIC) {
    float* slab = (float*)(ws + AGGT_OFF) + (size_t)ks * SLAB_FLTS;
#pragma unroll
    for (int m = 0; m < 4; ++m)
#pragma unroll
      for (int r = 0; r < 4; ++r) {
        int c = ct * 64 + m * 16 + lk * 4 + r;
        int w = wv * 16 + lrow;
        slab[(size_t)(c * W_ + w) * B_ + b] = acc[m][r] * sc;
      }
  } else {
    float* slab = (float*)(ws + AGGT_OFF);
#pragma unroll
    for (int m = 0; m < 4; ++m)
#pragma unroll
      for (int r = 0; r < 4; ++r) {
        int c = ct * 64 + m * 16 + lk * 4 + r;
        int w = wv * 16 + lrow;
        atomicAdd(&slab[(size_t)(c * W_ + w) * B_ + b], acc[m][r] * sc);
      }
  }
}

// ---------------- K3: part[kb][o*32+b] = sum_{k in kb-chunk} wf[o][k] * aggT[k][b] ----------------
// 256 blocks = 8 o-tiles x 32 k-splits; non-atomic partial stores (no init needed).
__global__ __launch_bounds__(256) void k3_final(const float* __restrict__ wf,
                                                const char* __restrict__ ws,
                                                float* __restrict__ part, int nslab) {
  __shared__ __align__(16) float wfl[64][68];
  __shared__ __align__(16) float agl[64][32];
  const int t = threadIdx.x;
  const int ot = blockIdx.x >> 5;
  const int kb = blockIdx.x & 31;
  const int o_base = ot * 64;
  const int k_base = kb * 512;
  const float* aggT = (const float*)(ws + AGGT_OFF);

  const int og = t >> 3, bg = t & 7;
  float a00 = 0.f, a01 = 0.f, a02 = 0.f, a03 = 0.f;
  float a10 = 0.f, a11 = 0.f, a12 = 0.f, a13 = 0.f;

  const int lr = t >> 2;
  const int lc = (t & 3) * 16;
  const int ac = (t & 3) * 8;

  for (int kc = 0; kc < 8; ++kc) {
    int k0 = k_base + kc * 64;
#pragma unroll
    for (int q = 0; q < 4; ++q)
      *(float4*)&wfl[lr][lc + q * 4] =
          *(const float4*)&wf[(size_t)(o_base + lr) * 16384 + k0 + lc + q * 4];
#pragma unroll
    for (int q = 0; q < 2; ++q) {
      size_t idx = (size_t)(k0 + lr) * 32 + ac + q * 4;
      float4 v = *(const float4*)&aggT[idx];
      for (int s = 1; s < nslab; ++s) {
        float4 u = *(const float4*)&aggT[(size_t)s * SLAB_FLTS + idx];
        v.x += u.x; v.y += u.y; v.z += u.z; v.w += u.w;
      }
      *(float4*)&agl[lr][ac + q * 4] = v;
    }
    __syncthreads();
#pragma unroll 8
    for (int k = 0; k < 64; ++k) {
      float w0 = wfl[og * 2][k];
      float w1 = wfl[og * 2 + 1][k];
      float4 av = *(const float4*)&agl[k][bg * 4];
      a00 += w0 * av.x; a01 += w0 * av.y; a02 += w0 * av.z; a03 += w0 * av.w;
      a10 += w1 * av.x; a11 += w1 * av.y; a12 += w1 * av.z; a13 += w1 * av.w;
    }
    __syncthreads();
  }
  float* dst = part + (size_t)kb * 16384;
  int o0 = o_base + og * 2;
  int bb = bg * 4;
  dst[o0 * 32 + bb + 0] = a00;
  dst[o0 * 32 + bb + 1] = a01;
  dst[o0 * 32 + bb + 2] = a02;
  dst[o0 * 32 + bb + 3] = a03;
  dst[(o0 + 1) * 32 + bb + 0] = a10;
  dst[(o0 + 1) * 32 + bb + 1] = a11;
  dst[(o0 + 1) * 32 + bb + 2] = a12;
  dst[(o0 + 1) * 32 + bb + 3] = a13;
}

// ---------------- K4: reduce partials + final BN + ReLU ----------------
__global__ void k4_finalize(const float* __restrict__ bf, const float* __restrict__ gf,
                            const float* __restrict__ bef, const float* __restrict__ mf,
                            const float* __restrict__ vf, const float* __restrict__ part,
                            float* __restrict__ out) {
  int i = blockIdx.x * 256 + threadIdx.x;  // 0..16383
  int o = i >> 5, b = i & 31;
  float v = 0.f;
#pragma unroll
  for (int kb = 0; kb < 32; ++kb) v += part[(size_t)kb * 16384 + i];
  float s = gf[o] * rsqrtf(vf[o] + EPS_);
  float r = (v + bf[o] - mf[o]) * s + bef[o];
  out[b * OUT_ + o] = fmaxf(r, 0.f);
}

extern "C" void kernel_launch(void* const* d_in, const int* in_sizes, int n_in,
                              void* d_out, int out_size, void* d_ws, size_t ws_size,
                              hipStream_t stream) {
  const float* xyz     = (const float*)d_in[0];
  const float* feature = (const float*)d_in[1];
  const float* w1 = (const float*)d_in[3];
  const float* b1 = (const float*)d_in[4];
  const float* g1 = (const float*)d_in[5];
  const float* be1 = (const float*)d_in[6];
  const float* m1 = (const float*)d_in[7];
  const float* v1 = (const float*)d_in[8];
  const float* w2 = (const float*)d_in[9];
  const float* b2 = (const float*)d_in[10];
  const float* g2 = (const float*)d_in[11];
  const float* be2 = (const float*)d_in[12];
  const float* m2 = (const float*)d_in[13];
  const float* v2 = (const float*)d_in[14];
  const float* w3 = (const float*)d_in[15];
  const float* b3 = (const float*)d_in[16];
  const float* g3 = (const float*)d_in[17];
  const float* be3 = (const float*)d_in[18];
  const float* m3 = (const float*)d_in[19];
  const float* v3 = (const float*)d_in[20];
  const float* wf = (const float*)d_in[21];
  const float* bf = (const float*)d_in[22];
  const float* gf = (const float*)d_in[23];
  const float* bef = (const float*)d_in[24];
  const float* mf = (const float*)d_in[25];
  const float* vf = (const float*)d_in[26];

  char* ws = (char*)d_ws;
  const bool four = ws_size >= (size_t)WS_NEED4;
  if (!four && ws_size < (size_t)WS_NEED1) return;
  float* part = (float*)(ws + (four ? PART4_OFF : PART1_OFF));

  k0_fuse<<<1, 64, 0, stream>>>(w1, b1, g1, be1, m1, v1,
                                w2, b2, g2, be2, m2, v2,
                                w3, b3, g3, be3, m3, v3, ws);
  k1_weightnet<<<512, 256, 0, stream>>>(xyz, ws);
  if (four) {
    k2_agg<false><<<512, 256, 0, stream>>>(feature, ws);
    k3_final<<<256, 256, 0, stream>>>(wf, ws, part, 4);
  } else {
    // fallback: single accumulation slab (needs zeroing once per call)
    hipMemsetAsync(ws + AGGT_OFF, 0, 2097152, stream);
    k2_agg<true><<<512, 256, 0, stream>>>(feature, ws);
    k3_final<<<256, 256, 0, stream>>>(wf, ws, part, 1);
  }
  k4_finalize<<<64, 256, 0, stream>>>(bf, gf, bef, mf, vf, part, (float*)d_out);
}

// Round 4
// 81.726 us; speedup vs baseline: 2.5729x; 1.3944x over previous
//
#include <hip/hip_runtime.h>
#include <hip/hip_bf16.h>

#define B_ 32
#define N_ 4096
#define C_ 256
#define W_ 64
#define OUT_ 512
#define EPS_ 1e-5f

typedef __attribute__((ext_vector_type(8))) short short8;
typedef __attribute__((ext_vector_type(4))) float floatx4;

// workspace layout (bytes)
#define WT_OFF     0                    // wt bf16 [b][w][n] = 16 MB
#define SLABS_OFF  16777216             // 8 slabs f32 [ks][b][cw] = 16 MB
#define AGGF_OFF   33554432             // aggF f32 [cw][b] = 2 MB
#define PART_OFF   35651584             // k3 partials [kb][o*32+b] = 2 MB
#define WS_NEEDED  37748736

__device__ __forceinline__ ushort f2bf(float f) {
  unsigned u = __builtin_bit_cast(unsigned, f);
  unsigned r = (u + 0x7fffu + ((u >> 16) & 1u)) >> 16;  // RTNE
  return (ushort)r;
}
__device__ __forceinline__ unsigned pk2(float a, float b) {
  return (unsigned)f2bf(a) | ((unsigned)f2bf(b) << 16);
}

// ---------------- K1: fuse BN + WeightNet (layer1 scalar, layers 2/3 MFMA) ----------------
// 512 blocks (b x 16 n-tiles) x 256 thr. Weight fusing done per-block (L2-hot reads).
__global__ __launch_bounds__(256) void k1_weightnet(
    const float* __restrict__ xyz,
    const float* __restrict__ w1, const float* __restrict__ b1,
    const float* __restrict__ g1, const float* __restrict__ be1,
    const float* __restrict__ m1, const float* __restrict__ v1,
    const float* __restrict__ w2, const float* __restrict__ b2,
    const float* __restrict__ g2, const float* __restrict__ be2,
    const float* __restrict__ m2, const float* __restrict__ v2,
    const float* __restrict__ w3, const float* __restrict__ b3,
    const float* __restrict__ g3, const float* __restrict__ be3,
    const float* __restrict__ m3, const float* __restrict__ v3,
    ushort* __restrict__ wt) {
  __shared__ __align__(16) ushort h_lds[256 * 72];   // also reused as T[64][132] u32
  __shared__ __align__(16) ushort w2_lds[64 * 72];
  __shared__ __align__(16) ushort w3_lds[64 * 72];
  __shared__ float w1l[192];
  __shared__ float b1l[64];
  __shared__ float b2_lds[64];
  __shared__ float b3_lds[64];

  const int t = threadIdx.x;
  const int blk = blockIdx.x;
  const int b = blk >> 4;
  const int n0 = (blk & 15) << 8;

  // ---- per-block BN fusing (64 threads) ----
  if (t < 64) {
    float s1 = g1[t] * rsqrtf(v1[t] + EPS_);
#pragma unroll
    for (int j = 0; j < 3; ++j) w1l[t * 3 + j] = w1[t * 3 + j] * s1;
    b1l[t] = (b1[t] - m1[t]) * s1 + be1[t];

    float s2 = g2[t] * rsqrtf(v2[t] + EPS_);
    unsigned* w2row = (unsigned*)&w2_lds[t * 72];
#pragma unroll
    for (int q = 0; q < 16; ++q) {
      float4 v = *(const float4*)&w2[t * 64 + q * 4];
      w2row[q * 2] = pk2(v.x * s2, v.y * s2);
      w2row[q * 2 + 1] = pk2(v.z * s2, v.w * s2);
    }
    w2row[32] = 0; w2row[33] = 0; w2row[34] = 0; w2row[35] = 0;
    b2_lds[t] = (b2[t] - m2[t]) * s2 + be2[t];

    float s3 = g3[t] * rsqrtf(v3[t] + EPS_);
    unsigned* w3row = (unsigned*)&w3_lds[t * 72];
#pragma unroll
    for (int q = 0; q < 16; ++q) {
      float4 v = *(const float4*)&w3[t * 64 + q * 4];
      w3row[q * 2] = pk2(v.x * s3, v.y * s3);
      w3row[q * 2 + 1] = pk2(v.z * s3, v.w * s3);
    }
    w3row[32] = 0; w3row[33] = 0; w3row[34] = 0; w3row[35] = 0;
    b3_lds[t] = (b3[t] - m3[t]) * s3 + be3[t];
  }
  __syncthreads();

  // ---- layer 1 (K=3), one point per thread, h1 bf16 -> LDS ----
  const int n = n0 + t;
  const float* xp = xyz + ((size_t)b * N_ + n) * 3;
  float x0 = xp[0], x1 = xp[1], x2 = xp[2];
  unsigned* hrow = (unsigned*)&h_lds[t * 72];
#pragma unroll 4
  for (int cp = 0; cp < 32; ++cp) {
    int c0 = cp * 2, c1 = cp * 2 + 1;
    float a0 = fmaxf(b1l[c0] + w1l[c0 * 3] * x0 + w1l[c0 * 3 + 1] * x1 + w1l[c0 * 3 + 2] * x2, 0.f);
    float a1 = fmaxf(b1l[c1] + w1l[c1 * 3] * x0 + w1l[c1 * 3 + 1] * x1 + w1l[c1 * 3 + 2] * x2, 0.f);
    hrow[cp] = pk2(a0, a1);
  }
  __syncthreads();

  const int wv = t >> 6, lane = t & 63;
  const int lrow = lane & 15, lk = lane >> 4;

  // ---- layer 2: per-wave GEMM 64pts x 64ch, K=64 ----
  floatx4 acc[4][4];
#pragma unroll
  for (int mt = 0; mt < 4; ++mt)
#pragma unroll
    for (int nt = 0; nt < 4; ++nt) acc[mt][nt] = (floatx4){0.f, 0.f, 0.f, 0.f};

#pragma unroll
  for (int ks = 0; ks < 2; ++ks) {
    short8 afr[4], bfr[4];
#pragma unroll
    for (int mt = 0; mt < 4; ++mt)
      afr[mt] = *(const short8*)&h_lds[(wv * 64 + mt * 16 + lrow) * 72 + ks * 32 + lk * 8];
#pragma unroll
    for (int nt = 0; nt < 4; ++nt)
      bfr[nt] = *(const short8*)&w2_lds[(nt * 16 + lrow) * 72 + ks * 32 + lk * 8];
#pragma unroll
    for (int mt = 0; mt < 4; ++mt)
#pragma unroll
      for (int nt = 0; nt < 4; ++nt)
        acc[mt][nt] = __builtin_amdgcn_mfma_f32_16x16x32_bf16(afr[mt], bfr[nt], acc[mt][nt], 0, 0, 0);
  }
  // bias+relu -> h2 (wave-private rows; reads precede writes within the wave)
#pragma unroll
  for (int mt = 0; mt < 4; ++mt)
#pragma unroll
    for (int nt = 0; nt < 4; ++nt) {
      float bias = b2_lds[nt * 16 + lrow];
#pragma unroll
      for (int r = 0; r < 4; ++r) {
        float v = fmaxf(acc[mt][nt][r] + bias, 0.f);
        h_lds[(wv * 64 + mt * 16 + lk * 4 + r) * 72 + nt * 16 + lrow] = f2bf(v);
      }
    }

  // ---- layer 3 ----
  floatx4 acc3[4][4];
#pragma unroll
  for (int mt = 0; mt < 4; ++mt)
#pragma unroll
    for (int nt = 0; nt < 4; ++nt) acc3[mt][nt] = (floatx4){0.f, 0.f, 0.f, 0.f};

#pragma unroll
  for (int ks = 0; ks < 2; ++ks) {
    short8 afr[4], bfr[4];
#pragma unroll
    for (int mt = 0; mt < 4; ++mt)
      afr[mt] = *(const short8*)&h_lds[(wv * 64 + mt * 16 + lrow) * 72 + ks * 32 + lk * 8];
#pragma unroll
    for (int nt = 0; nt < 4; ++nt)
      bfr[nt] = *(const short8*)&w3_lds[(nt * 16 + lrow) * 72 + ks * 32 + lk * 8];
#pragma unroll
    for (int mt = 0; mt < 4; ++mt)
#pragma unroll
      for (int nt = 0; nt < 4; ++nt)
        acc3[mt][nt] = __builtin_amdgcn_mfma_f32_16x16x32_bf16(afr[mt], bfr[nt], acc3[mt][nt], 0, 0, 0);
  }

  // ---- bias+relu -> transpose in LDS -> coalesced uint4 stores ----
  __syncthreads();  // all layer-3 LDS reads done before h_lds is reused as T
  unsigned* T = (unsigned*)h_lds;  // T[64 ch][132 u32], row = 528 B (16B aligned)
#pragma unroll
  for (int mt = 0; mt < 4; ++mt)
#pragma unroll
    for (int nt = 0; nt < 4; ++nt) {
      float bias = b3_lds[nt * 16 + lrow];
      float v0 = fmaxf(acc3[mt][nt][0] + bias, 0.f);
      float v1 = fmaxf(acc3[mt][nt][1] + bias, 0.f);
      float v2 = fmaxf(acc3[mt][nt][2] + bias, 0.f);
      float v3 = fmaxf(acc3[mt][nt][3] + bias, 0.f);
      int ch = nt * 16 + lrow;
      int pp = (wv * 64 + mt * 16 + lk * 4) >> 1;  // pt-pair index
      T[ch * 132 + pp] = pk2(v0, v1);
      T[ch * 132 + pp + 1] = pk2(v2, v3);
    }
  __syncthreads();

  const int ch = t >> 2, q = t & 3;
  unsigned* wtu = (unsigned*)wt;
  size_t obase = ((size_t)(b * W_ + ch)) * (N_ / 2) + (n0 >> 1);
#pragma unroll
  for (int j = 0; j < 8; ++j) {
    int col = q * 4 + j * 16;
    uint4 vv = *(const uint4*)&T[ch * 132 + col];
    *(uint4*)&wtu[obase + col] = vv;
  }
}

// ---------------- K2: agg slab[ks][b][c*64+w] = sum_{k-chunk} feat[b][c][k] * wt[b][w][k] ----------------
// 2048 single-wave blocks: blk = (b*8 + ks)*8 + ct. Wave = 32 c-rows x 64 w x 512 k.
// No LDS, no barriers; explicit 4-deep register prefetch.
__global__ __launch_bounds__(64, 2) void k2_agg(const float* __restrict__ feature,
                                                const ushort* __restrict__ wt,
                                                float* __restrict__ slabs) {
  const int lane = threadIdx.x;
  const int lrow = lane & 15, lk = lane >> 4;
  const int blk = blockIdx.x;
  const int ct = blk & 7;          // ct lowest-stride? no: see mapping note
  const int ks = (blk >> 3) & 7;
  const int b = blk >> 6;
  // mapping: blk = (b*8 + ks)*8 + ct  -> blocks sharing the wt slice (same b,ks)
  // are stride-1... we want them stride-8 (same XCD). Swap roles:
  const int ks2 = blk & 7;
  const int ct2 = (blk >> 3) & 7;
  // final: ks = blk&7, ct = (blk>>3)&7  (wt-sharing blocks at stride 8 -> same XCD)
  const int KS = ks2, CT = ct2;
  (void)ct; (void)ks;

  const float* fA = feature + ((size_t)(b * C_ + CT * 32 + lrow)) * N_ + KS * 512 + lk * 8;
  const float* fB = fA + (size_t)16 * N_;
  const ushort* w0 = wt + ((size_t)(b * W_ + lrow)) * N_ + KS * 512 + lk * 8;

  floatx4 acc[2][4];
#pragma unroll
  for (int m = 0; m < 2; ++m)
#pragma unroll
    for (int g = 0; g < 4; ++g) acc[m][g] = (floatx4){0.f, 0.f, 0.f, 0.f};

  float4 A[4][4];
  short8 Bv[4][4];

#define LOADSTEP(s, kof)                                        \
  do {                                                          \
    A[s][0] = *(const float4*)(fA + (kof));                     \
    A[s][1] = *(const float4*)(fA + (kof) + 4);                 \
    A[s][2] = *(const float4*)(fB + (kof));                     \
    A[s][3] = *(const float4*)(fB + (kof) + 4);                 \
    Bv[s][0] = *(const short8*)(w0 + (kof));                    \
    Bv[s][1] = *(const short8*)(w0 + (kof) + 16 * N_);          \
    Bv[s][2] = *(const short8*)(w0 + (kof) + 32 * N_);          \
    Bv[s][3] = *(const short8*)(w0 + (kof) + 48 * N_);          \
  } while (0)

  LOADSTEP(0, 0);
  LOADSTEP(1, 32);
  LOADSTEP(2, 64);
  LOADSTEP(3, 96);

#pragma unroll
  for (int kk = 0; kk < 16; ++kk) {
    const int st = kk & 3;
    union { unsigned u[4]; short8 s8; } p0, p1;
    p0.u[0] = pk2(A[st][0].x, A[st][0].y);
    p0.u[1] = pk2(A[st][0].z, A[st][0].w);
    p0.u[2] = pk2(A[st][1].x, A[st][1].y);
    p0.u[3] = pk2(A[st][1].z, A[st][1].w);
    p1.u[0] = pk2(A[st][2].x, A[st][2].y);
    p1.u[1] = pk2(A[st][2].z, A[st][2].w);
    p1.u[2] = pk2(A[st][3].x, A[st][3].y);
    p1.u[3] = pk2(A[st][3].z, A[st][3].w);
#pragma unroll
    for (int g = 0; g < 4; ++g)
      acc[0][g] = __builtin_amdgcn_mfma_f32_16x16x32_bf16(p0.s8, Bv[st][g], acc[0][g], 0, 0, 0);
#pragma unroll
    for (int g = 0; g < 4; ++g)
      acc[1][g] = __builtin_amdgcn_mfma_f32_16x16x32_bf16(p1.s8, Bv[st][g], acc[1][g], 0, 0, 0);
    if (kk < 12) LOADSTEP(st, (kk + 4) * 32);
  }
#undef LOADSTEP

  const float sc = 1.f / 4096.f;
  float* slab = slabs + ((size_t)(KS * B_ + b)) * 16384;
#pragma unroll
  for (int m = 0; m < 2; ++m)
#pragma unroll
    for (int g = 0; g < 4; ++g)
#pragma unroll
      for (int r = 0; r < 4; ++r) {
        int c = CT * 32 + m * 16 + lk * 4 + r;
        int w = g * 16 + lrow;
        slab[c * 64 + w] = acc[m][g][r] * sc;
      }
}

// ---------------- K2b: aggF[cw][b] = sum_ks slab[ks][b][cw]  (transpose-reduce) ----------------
__global__ __launch_bounds__(256) void k2b_reduce(const float* __restrict__ slabs,
                                                  float* __restrict__ aggF) {
  __shared__ __align__(16) float tile[32][68];
  const int t = threadIdx.x;
  const int cw0 = blockIdx.x * 64;
  const int b = t >> 3, c8 = (t & 7) * 8;

  float4 s0 = {0.f, 0.f, 0.f, 0.f}, s1 = {0.f, 0.f, 0.f, 0.f};
#pragma unroll
  for (int ks = 0; ks < 8; ++ks) {
    const float* p = slabs + ((size_t)(ks * B_ + b)) * 16384 + cw0 + c8;
    float4 x0 = *(const float4*)p;
    float4 x1 = *(const float4*)(p + 4);
    s0.x += x0.x; s0.y += x0.y; s0.z += x0.z; s0.w += x0.w;
    s1.x += x1.x; s1.y += x1.y; s1.z += x1.z; s1.w += x1.w;
  }
  *(float4*)&tile[b][c8] = s0;
  *(float4*)&tile[b][c8 + 4] = s1;
  __syncthreads();

  const int cw = t >> 2, q = t & 3;
  float4 o0, o1;
  o0.x = tile[q * 4 + 0][cw]; o0.y = tile[q * 4 + 1][cw];
  o0.z = tile[q * 4 + 2][cw]; o0.w = tile[q * 4 + 3][cw];
  o1.x = tile[16 + q * 4 + 0][cw]; o1.y = tile[16 + q * 4 + 1][cw];
  o1.z = tile[16 + q * 4 + 2][cw]; o1.w = tile[16 + q * 4 + 3][cw];
  *(float4*)&aggF[(size_t)(cw0 + cw) * B_ + q * 4] = o0;
  *(float4*)&aggF[(size_t)(cw0 + cw) * B_ + 16 + q * 4] = o1;
}

// ---------------- K3: part[kb][o*32+b] = sum_{k-chunk} wf[o][k] * aggF[k][b] ----------------
__global__ __launch_bounds__(256) void k3_final(const float* __restrict__ wf,
                                                const float* __restrict__ aggF,
                                                float* __restrict__ part) {
  __shared__ __align__(16) float wfl[64][68];
  __shared__ __align__(16) float agl[64][32];
  const int t = threadIdx.x;
  const int ot = blockIdx.x >> 5;
  const int kb = blockIdx.x & 31;
  const int o_base = ot * 64;
  const int k_base = kb * 512;

  const int og = t >> 3, bg = t & 7;
  float a00 = 0.f, a01 = 0.f, a02 = 0.f, a03 = 0.f;
  float a10 = 0.f, a11 = 0.f, a12 = 0.f, a13 = 0.f;

  const int lr = t >> 2;
  const int lc = (t & 3) * 16;
  const int ac = (t & 3) * 8;

  for (int kc = 0; kc < 8; ++kc) {
    int k0 = k_base + kc * 64;
#pragma unroll
    for (int q = 0; q < 4; ++q)
      *(float4*)&wfl[lr][lc + q * 4] =
          *(const float4*)&wf[(size_t)(o_base + lr) * 16384 + k0 + lc + q * 4];
#pragma unroll
    for (int q = 0; q < 2; ++q)
      *(float4*)&agl[lr][ac + q * 4] =
          *(const float4*)&aggF[(size_t)(k0 + lr) * B_ + ac + q * 4];
    __syncthreads();
#pragma unroll 8
    for (int k = 0; k < 64; ++k) {
      float w0 = wfl[og * 2][k];
      float w1 = wfl[og * 2 + 1][k];
      float4 av = *(const float4*)&agl[k][bg * 4];
      a00 += w0 * av.x; a01 += w0 * av.y; a02 += w0 * av.z; a03 += w0 * av.w;
      a10 += w1 * av.x; a11 += w1 * av.y; a12 += w1 * av.z; a13 += w1 * av.w;
    }
    __syncthreads();
  }
  float* dst = part + (size_t)kb * 16384;
  int o0 = o_base + og * 2;
  int bb = bg * 4;
  dst[o0 * 32 + bb + 0] = a00;
  dst[o0 * 32 + bb + 1] = a01;
  dst[o0 * 32 + bb + 2] = a02;
  dst[o0 * 32 + bb + 3] = a03;
  dst[(o0 + 1) * 32 + bb + 0] = a10;
  dst[(o0 + 1) * 32 + bb + 1] = a11;
  dst[(o0 + 1) * 32 + bb + 2] = a12;
  dst[(o0 + 1) * 32 + bb + 3] = a13;
}

// ---------------- K4: reduce partials + final BN + ReLU ----------------
__global__ void k4_finalize(const float* __restrict__ bf, const float* __restrict__ gf,
                            const float* __restrict__ bef, const float* __restrict__ mf,
                            const float* __restrict__ vf, const float* __restrict__ part,
                            float* __restrict__ out) {
  int i = blockIdx.x * 256 + threadIdx.x;  // 0..16383
  int o = i >> 5, b = i & 31;
  float v = 0.f;
#pragma unroll
  for (int kb = 0; kb < 32; ++kb) v += part[(size_t)kb * 16384 + i];
  float s = gf[o] * rsqrtf(vf[o] + EPS_);
  float r = (v + bf[o] - mf[o]) * s + bef[o];
  out[b * OUT_ + o] = fmaxf(r, 0.f);
}

extern "C" void kernel_launch(void* const* d_in, const int* in_sizes, int n_in,
                              void* d_out, int out_size, void* d_ws, size_t ws_size,
                              hipStream_t stream) {
  const float* xyz     = (const float*)d_in[0];
  const float* feature = (const float*)d_in[1];
  const float* w1 = (const float*)d_in[3];
  const float* b1 = (const float*)d_in[4];
  const float* g1 = (const float*)d_in[5];
  const float* be1 = (const float*)d_in[6];
  const float* m1 = (const float*)d_in[7];
  const float* v1 = (const float*)d_in[8];
  const float* w2 = (const float*)d_in[9];
  const float* b2 = (const float*)d_in[10];
  const float* g2 = (const float*)d_in[11];
  const float* be2 = (const float*)d_in[12];
  const float* m2 = (const float*)d_in[13];
  const float* v2 = (const float*)d_in[14];
  const float* w3 = (const float*)d_in[15];
  const float* b3 = (const float*)d_in[16];
  const float* g3 = (const float*)d_in[17];
  const float* be3 = (const float*)d_in[18];
  const float* m3 = (const float*)d_in[19];
  const float* v3 = (const float*)d_in[20];
  const float* wf = (const float*)d_in[21];
  const float* bf = (const float*)d_in[22];
  const float* gf = (const float*)d_in[23];
  const float* bef = (const float*)d_in[24];
  const float* mf = (const float*)d_in[25];
  const float* vf = (const float*)d_in[26];

  char* ws = (char*)d_ws;
  if (ws_size < (size_t)WS_NEEDED) return;
  ushort* wt   = (ushort*)(ws + WT_OFF);
  float* slabs = (float*)(ws + SLABS_OFF);
  float* aggF  = (float*)(ws + AGGF_OFF);
  float* part  = (float*)(ws + PART_OFF);

  k1_weightnet<<<512, 256, 0, stream>>>(xyz,
                                        w1, b1, g1, be1, m1, v1,
                                        w2, b2, g2, be2, m2, v2,
                                        w3, b3, g3, be3, m3, v3, wt);
  k2_agg<<<2048, 64, 0, stream>>>(feature, wt, slabs);
  k2b_reduce<<<256, 256, 0, stream>>>(slabs, aggF);
  k3_final<<<256, 256, 0, stream>>>(wf, aggF, part);
  k4_finalize<<<64, 256, 0, stream>>>(bf, gf, bef, mf, vf, part, (float*)d_out);
}